// Round 31
// baseline (140.558 us; speedup 1.0000x reference)
//
#include <hip/hip_runtime.h>
#include <hip/hip_bf16.h>

typedef __attribute__((ext_vector_type(4))) float f32x4;
typedef __attribute__((ext_vector_type(8))) short s16x8;
typedef __attribute__((ext_vector_type(4))) int i32x4;
typedef __attribute__((address_space(3))) unsigned char lds_t;
typedef __attribute__((address_space(1))) const unsigned char glob_t;

#define TFDIM 4096
#define DMODEL 768
#define NHEAD 12
#define HDIM 64
#define NLB 6
#define SLOTSZ 3145728   // shorts per partial slot: 12*4096*64

static __device__ __forceinline__ unsigned short f2bf(float f) {
    union { float f; unsigned u; } x; x.f = f;
    unsigned r = x.u + 0x7fff + ((x.u >> 16) & 1);
    return (unsigned short)(r >> 16);
}

static __device__ __forceinline__ float bf2f(unsigned short u) {
    return __uint_as_float(((unsigned)u) << 16);
}

static __device__ __forceinline__ float exp2_hw(float x) {
    float r;
    asm("v_exp_f32 %0, %1\n\ts_nop 0" : "=v"(r) : "v"(x));
    return r;
}

static __device__ __forceinline__ unsigned cvtpk_bf16(float lo, float hi) {
    unsigned r;
    asm("v_cvt_pk_bf16_f32 %0, %1, %2" : "=v"(r) : "v"(lo), "v"(hi));
    return r;
}

// swap32 then swap16: from packed S-pairs (w_f, w_{f+1}) produce A0 (a) and A2 (b)
static __device__ __forceinline__ void xpose_pair(unsigned& a, unsigned& b) {
    asm volatile("v_permlane32_swap_b32 %0, %1" : "+v"(a), "+v"(b));
    asm volatile("v_permlane16_swap_b32 %0, %1" : "+v"(a), "+v"(b));
}

// ---------------- combined prep kernel ----------------
// blocks [0,432): wqkv transpose tiles; [432,576): wo transpose tiles;
// [576,624): Lacc zero; [624,3696): pack_x; [3696,6768): Oacc zero (branch-2 unused).
__global__ __launch_bounds__(256) void prep_kernel(
    const float* __restrict__ x, unsigned short* __restrict__ xb,
    const float* __restrict__ Wq, const float* __restrict__ Wk, const float* __restrict__ Wv,
    const float* __restrict__ bq, const float* __restrict__ bk, const float* __restrict__ bv,
    unsigned short* __restrict__ Wt, float* __restrict__ bias,
    const float* __restrict__ Wo, unsigned short* __restrict__ Wot,
    float* __restrict__ Lacc, float* __restrict__ Oacc) {
    __shared__ unsigned short tile[64][65];
    int b = blockIdx.x;
    int t = threadIdx.x;
    if (b < 432) {
        int qkv = b / 144, rem = b - qkv * 144, h = rem / 12, kt = rem - h * 12;
        const float* W = (qkv == 0) ? Wq : ((qkv == 1) ? Wk : Wv);
        int trow = t >> 2, tco = (t & 3) << 4;
        const float* src = &W[((size_t)h * 768 + kt * 64 + trow) * 64 + tco];
#pragma unroll
        for (int j = 0; j < 4; j++) {
            float4 v = *(const float4*)&src[j * 4];
            tile[trow][tco + j * 4 + 0] = f2bf(v.x);
            tile[trow][tco + j * 4 + 1] = f2bf(v.y);
            tile[trow][tco + j * 4 + 2] = f2bf(v.z);
            tile[trow][tco + j * 4 + 3] = f2bf(v.w);
        }
        if (kt == 0 && t < 64) {
            const float* bb = (qkv == 0) ? bq : ((qkv == 1) ? bk : bv);
            bias[qkv * 768 + h * 64 + t] = bb[h * 64 + t];
        }
        __syncthreads();
        unsigned short vals[16];
#pragma unroll
        for (int j = 0; j < 16; j++) vals[j] = tile[tco + j][trow];
        unsigned short* dst = &Wt[(size_t)(qkv * 768 + h * 64 + trow) * 768 + kt * 64 + tco];
        *(s16x8*)&dst[0] = *(const s16x8*)&vals[0];
        *(s16x8*)&dst[8] = *(const s16x8*)&vals[8];
    } else if (b < 576) {
        int bb = b - 432;
        int nt = bb / 12, kt = bb - nt * 12;
        int trow = t >> 2, tco = (t & 3) << 4;
        const float* src = &Wo[(size_t)(kt * 64 + trow) * 768 + nt * 64 + tco];
#pragma unroll
        for (int j = 0; j < 4; j++) {
            float4 v = *(const float4*)&src[j * 4];
            tile[trow][tco + j * 4 + 0] = f2bf(v.x);
            tile[trow][tco + j * 4 + 1] = f2bf(v.y);
            tile[trow][tco + j * 4 + 2] = f2bf(v.z);
            tile[trow][tco + j * 4 + 3] = f2bf(v.w);
        }
        __syncthreads();
        unsigned short vals[16];
#pragma unroll
        for (int j = 0; j < 16; j++) vals[j] = tile[tco + j][trow];
        unsigned short* dst = &Wot[(size_t)(nt * 64 + trow) * 768 + kt * 64 + tco];
        *(s16x8*)&dst[0] = *(const s16x8*)&vals[0];
        *(s16x8*)&dst[8] = *(const s16x8*)&vals[8];
    } else if (b < 624) {
        int i = (b - 576) * 256 + t;
        if (i < NHEAD * TFDIM / 4) {
            float4 z = {0.f, 0.f, 0.f, 0.f};
            ((float4*)Lacc)[i] = z;
        }
    } else if (b < 3696) {
        int i = (b - 624) * 256 + t;
        if (i < TFDIM * DMODEL / 4) {
            float4 v = ((const float4*)x)[i];
            ushort4 o;
            o.x = f2bf(v.x); o.y = f2bf(v.y); o.z = f2bf(v.z); o.w = f2bf(v.w);
            ((ushort4*)xb)[i] = o;
        }
    } else {
        int i = (b - 3696) * 256 + t;
        if (i < TFDIM * DMODEL / 4) {
            float4 z = {0.f, 0.f, 0.f, 0.f};
            ((float4*)Oacc)[i] = z;
        }
    }
}

// ---------------- GEMM: C = A[M,K] * Bt[N,K]^T + bias ----------------
// BK=64, [128][64]-short LDS tiles, full 8-granule XOR swizzle (slot ^ (row&7)),
// B (and AX=0 A) staged via global_load_lds with pre-swizzled source.
// AX=0: A bf16 DMA. AX=2: A = sum of n bf16 partial slots * rcp(Lacc) (fused
//       attention-merge; M-tile == q-block and BK == head, so n is uniform).
// EPI 0: fp32 row-major C. EPI 1: Q (pre-scaled log2e/8), K blocked64 (nbase<1536);
//        V blocks (nbase>=1536): LDS-transpose epilogue -> coalesced Vtg writes.
template <int EPI, int AX>
__global__ __launch_bounds__(256) void gemm_bt_kernel(
    const unsigned short* __restrict__ A,
    const unsigned short* __restrict__ PO01, const unsigned short* __restrict__ PO23,
    const float* __restrict__ LaccM,
    const unsigned short* __restrict__ Bt,
    const float* __restrict__ bias,
    float* __restrict__ Cf, unsigned short* __restrict__ Cb,
    unsigned short* __restrict__ Vtg,
    int M, int N, int K) {
    __shared__ __align__(16) unsigned short As[128 * 64];
    __shared__ __align__(16) unsigned short Bs[128 * 64];
    int tid = threadIdx.x;
    int w = tid >> 6, l = tid & 63, lr = l & 15, lg = l >> 4;
    int wm = w >> 1, wn = w & 1;

    int nwg = gridDim.x * gridDim.y;
    int flat = blockIdx.y * gridDim.x + blockIdx.x;
    int cpx = nwg >> 3;
    int swz = (flat & 7) * cpx + (flat >> 3);
    int bx = swz % gridDim.x, by = swz / gridDim.x;
    size_t mbase = (size_t)by * 128, nbase = (size_t)bx * 128;

    int drw = l >> 3, dslot = l & 7;
    int dg = (dslot ^ drw) << 3;
    f32x4 acc[4][4] = {};
    for (int k0 = 0; k0 < K; k0 += 64) {
        __syncthreads();
        if (AX == 2) {
            // fused attention-merge staging: sum n slots, normalize, cvt to bf16
            int h = k0 >> 6;
            int jq = (int)(mbase >> 7);
            int jqw = (h < NLB) ? jq : 31 - jq;
            int n = 1 + (jqw >> 3);
#pragma unroll
            for (int i = 0; i < 4; i++) {
                int idx = tid + i * 256;
                int row = idx >> 3, g = idx & 7;
                size_t off = ((size_t)(h * TFDIM) + mbase + row) * 64 + g * 8;
                float accv[8] = {};
                for (int s = 0; s < n; s++) {
                    const unsigned short* PO = (s < 2) ? (PO01 + (size_t)s * SLOTSZ)
                                                       : (PO23 + (size_t)(s - 2) * SLOTSZ);
                    s16x8 v = *(const s16x8*)&PO[off];
#pragma unroll
                    for (int j2 = 0; j2 < 8; j2++) accv[j2] += bf2f((unsigned short)v[j2]);
                }
                float rl = __builtin_amdgcn_rcpf(LaccM[h * TFDIM + mbase + row]);
                unsigned short us[8];
#pragma unroll
                for (int j2 = 0; j2 < 8; j2++) us[j2] = f2bf(accv[j2] * rl);
                *(s16x8*)&As[row * 64 + ((g ^ (row & 7)) << 3)] = *(const s16x8*)us;
            }
        } else {
#pragma unroll
            for (int j = 0; j < 4; j++) {
                int row = j * 32 + w * 8 + drw;
                __builtin_amdgcn_global_load_lds((glob_t*)&A[(mbase + row) * K + k0 + dg],
                                                 (lds_t*)&As[(j * 32 + w * 8) * 64], 16, 0, 0);
            }
        }
#pragma unroll
        for (int j = 0; j < 4; j++) {
            int row = j * 32 + w * 8 + drw;
            __builtin_amdgcn_global_load_lds((glob_t*)&Bt[(nbase + row) * K + k0 + dg],
                                             (lds_t*)&Bs[(j * 32 + w * 8) * 64], 16, 0, 0);
        }
        __syncthreads();
#pragma unroll
        for (int ks = 0; ks < 2; ks++) {
            s16x8 af[4], bfr[4];
#pragma unroll
            for (int m = 0; m < 4; m++) {
                int row = wm * 64 + m * 16 + lr;
                af[m] = *(const s16x8*)&As[row * 64 + (((ks * 4 + lg) ^ (row & 7)) << 3)];
            }
#pragma unroll
            for (int n2 = 0; n2 < 4; n2++) {
                int row = wn * 64 + n2 * 16 + lr;
                bfr[n2] = *(const s16x8*)&Bs[row * 64 + (((ks * 4 + lg) ^ (row & 7)) << 3)];
            }
#pragma unroll
            for (int m = 0; m < 4; m++)
#pragma unroll
                for (int n2 = 0; n2 < 4; n2++)
                    acc[m][n2] = __builtin_amdgcn_mfma_f32_16x16x32_bf16(af[m], bfr[n2], acc[m][n2], 0, 0, 0);
        }
    }
    if (EPI == 1 && nbase >= 1536) {
        // V-block: LDS-bounce transpose -> coalesced Vtg writes.
        __syncthreads();
        unsigned short* L = (w < 2) ? &As[w * 4096] : &Bs[(w - 2) * 4096];
#pragma unroll
        for (int n2 = 0; n2 < 4; n2++) {
            int dloc = n2 * 16 + lr;
            float bv = bias[nbase + wn * 64 + dloc];
            int sw = (dloc & 7) << 3;
#pragma unroll
            for (int m = 0; m < 4; m++) {
                int tokloc = m * 16 + lg * 4;
                uint2 pw;
                pw.x = cvtpk_bf16(acc[m][n2][0] + bv, acc[m][n2][1] + bv);
                pw.y = cvtpk_bf16(acc[m][n2][2] + bv, acc[m][n2][3] + bv);
                *(uint2*)&L[dloc * 64 + (tokloc ^ sw)] = pw;
            }
        }
        __asm__ volatile("" ::: "memory");
        int hq = ((int)(nbase - 1536) >> 6) + wn;
        size_t vbase = (size_t)hq * 262144 + mbase + wm * 64;
#pragma unroll
        for (int it = 0; it < 8; it++) {
            int dl = it * 8 + (l >> 3);
            int t0 = (l & 7) * 8;
            s16x8 vv = *(const s16x8*)&L[dl * 64 + (t0 ^ ((dl & 7) << 3))];
            *(s16x8*)&Vtg[vbase + (size_t)dl * 4096 + t0] = vv;
        }
    } else {
#pragma unroll
        for (int m = 0; m < 4; m++) {
            size_t row0 = mbase + wm * 64 + m * 16 + lg * 4;
#pragma unroll
            for (int n2 = 0; n2 < 4; n2++) {
                size_t col = nbase + wn * 64 + n2 * 16 + lr;
                float bv = bias[col];
#pragma unroll
                for (int r = 0; r < 4; r++) {
                    float v = acc[m][n2][r] + bv;
                    if (EPI == 0) {
                        Cf[(row0 + r) * N + col] = v;
                    } else {
                        if (col < 768) v *= 0.18033688f;  // Q pre-scale: log2(e)/8
                        Cb[(((col >> 6) * 4096 + (row0 + r)) << 6) + (col & 63)] = f2bf(v);
                    }
                }
            }
        }
    }
}

// ---------------- flash attention, QBLK=128, 8 waves, kv-split chunks ----------------
// XCD head-clustering (r30 validated, FETCH -33%). PART=0: fp32 atomics.
// PART=1: non-atomic bf16 partial slots (r29, -11us).
template <int PART>
__global__ __launch_bounds__(512, 4) void attn_kernel(const unsigned short* __restrict__ qk,
                                                      const unsigned short* __restrict__ vtg,
                                                      float* __restrict__ Oacc,
                                                      float* __restrict__ Lacc,
                                                      unsigned short* __restrict__ PO01,
                                                      unsigned short* __restrict__ PO23) {
    __shared__ __align__(16) unsigned short Ks[3][64][64];
    __shared__ __align__(16) unsigned short Vs[3][64][64];

    int b = blockIdx.x;
    int xc = b & 7, j = b >> 3;
    int t3 = j / 3, rsel = j - t3 * 3;
    int h, r;
    if (xc & 1) {
        int ffull = (3 * xc + 1) >> 1;
        if (rsel == 0)      { h = ffull;     r = 2 * t3; }
        else if (rsel == 1) { h = ffull;     r = 2 * t3 + 1; }
        else                { h = ffull - 1; r = 2 * t3 + 1; }
    } else {
        int ffull = (3 * xc) >> 1;
        if (rsel == 0)      { h = ffull;     r = 2 * t3; }
        else if (rsel == 1) { h = ffull;     r = 2 * t3 + 1; }
        else                { h = ffull + 1; r = 2 * t3; }
    }
    int idx = 79 - r;
    int jqw, c, n;
    if (idx < 8)       { jqw = idx;               c = 0;              n = 1; }
    else if (idx < 24) { jqw = 8 + ((idx - 8) >> 1);  c = (idx - 8) & 1;  n = 2; }
    else if (idx < 48) { jqw = 16 + (idx - 24) / 3;   c = (idx - 24) % 3; n = 3; }
    else               { jqw = 24 + ((idx - 48) >> 2); c = (idx - 48) & 3; n = 4; }
    int W = 2 * jqw + 2;
    int base = W / n, rem = W % n;
    int len = base + (c < rem ? 1 : 0);
    int s0 = c * base + (c < rem ? c : rem);
    bool causal = (h < NLB);
    int jq = causal ? jqw : (31 - jqw);
    int qbase = jq * 128;
    int dkb = 2 * jq;
    int kb0 = (causal ? 0 : (62 - 2 * jqw)) + s0;
    int kb1 = kb0 + len - 1;

    const unsigned short* Q  = qk + (size_t)h * TFDIM * HDIM;
    const unsigned short* Kp = qk + (size_t)(NHEAD + h) * TFDIM * HDIM;
    const unsigned short* Vt = vtg + (size_t)h * HDIM * TFDIM;

    int tid = threadIdx.x, w = tid >> 6, l = tid & 63, lr = l & 15, lg = l >> 4;
    int qh = w >> 2, wq = w & 3;       // q-half, wave-within-half
    int dk = dkb + qh;                 // this wave's diagonal kv-block

    s16x8 qf[2];
    {
        size_t qrow = (size_t)(qbase + qh * 64 + wq * 16 + lr);
        qf[0] = *(const s16x8*)&Q[qrow * HDIM + lg * 8];
        qf[1] = *(const s16x8*)&Q[qrow * HDIM + 32 + lg * 8];
    }
    f32x4 oacc[4] = {};
    float lsum = 0.f;

    int drow = tid >> 3, dseg = tid & 7;
    int sg0 = (dseg ^ (drow & 7)) << 3;
    auto stage = [&](int buf, int kv) {
        __builtin_amdgcn_global_load_lds((glob_t*)(Kp + (size_t)(kv * 64 + drow) * HDIM + sg0),
                                         (lds_t*)&Ks[buf][w * 8][0], 16, 0, 0);
        __builtin_amdgcn_global_load_lds((glob_t*)(Vt + (size_t)drow * TFDIM + kv * 64 + sg0),
                                         (lds_t*)&Vs[buf][w * 8][0], 16, 0, 0);
    };

    stage(0, kb0);

    int cur = 0;
    int qcol = wq * 16 + lr;
    for (int kb = kb0; kb <= kb1; kb++) {
        bool more = (kb < kb1);
        if (more) {
            int nxt = (cur == 2) ? 0 : cur + 1;
            stage(nxt, kb + 1);
            asm volatile("s_waitcnt vmcnt(2)" ::: "memory");
        } else {
            asm volatile("s_waitcnt vmcnt(0)" ::: "memory");
        }
        __builtin_amdgcn_s_barrier();
        __builtin_amdgcn_sched_barrier(0);

        int kvbase = kb * 64;
        s16x8 vf[2][4];
#pragma unroll
        for (int ks = 0; ks < 2; ks++)
#pragma unroll
            for (int df = 0; df < 4; df++)
                vf[ks][df] = *(const s16x8*)&Vs[cur][df * 16 + lr][(ks * 32 + lg * 8) ^ ((lr & 7) << 3)];
        f32x4 s[4];
        __builtin_amdgcn_s_setprio(1);
#pragma unroll
        for (int f = 0; f < 4; f++) {
            s16x8 kf0 = *(const s16x8*)&Ks[cur][f * 16 + lr][(lg * 8) ^ ((lr & 7) << 3)];
            s16x8 kf1 = *(const s16x8*)&Ks[cur][f * 16 + lr][(32 + lg * 8) ^ ((lr & 7) << 3)];
            f32x4 z = {0.f, 0.f, 0.f, 0.f};
            z = __builtin_amdgcn_mfma_f32_16x16x32_bf16(kf0, qf[0], z, 0, 0, 0);
            z = __builtin_amdgcn_mfma_f32_16x16x32_bf16(kf1, qf[1], z, 0, 0, 0);
            s[f] = z;
        }
        __builtin_amdgcn_s_setprio(0);

        bool skip = causal ? (kb > dk) : (kb < dk);
        if (!skip) {
            if (kb == dk) {
                int qi = qbase + qh * 64 + qcol;
#pragma unroll
                for (int f = 0; f < 4; f++)
#pragma unroll
                    for (int r2 = 0; r2 < 4; r2++) {
                        int ki = kvbase + f * 16 + lg * 4 + r2;
                        bool keep = causal ? (qi >= ki) : (qi <= ki);
                        if (!keep) s[f][r2] = -1e30f;
                    }
            }
            float ls = 0.f;
            unsigned w0[4], w1[4];
#pragma unroll
            for (int f = 0; f < 4; f++) {
                float p0 = exp2_hw(s[f][0]);
                float p1 = exp2_hw(s[f][1]);
                float p2 = exp2_hw(s[f][2]);
                float p3 = exp2_hw(s[f][3]);
                ls += (p0 + p1) + (p2 + p3);
                w0[f] = cvtpk_bf16(p0, p1);
                w1[f] = cvtpk_bf16(p2, p3);
            }
            lsum += ls;
            xpose_pair(w0[0], w0[1]);
            xpose_pair(w1[0], w1[1]);
            xpose_pair(w0[2], w0[3]);
            xpose_pair(w1[2], w1[3]);
            union { unsigned u[4]; s16x8 v8; } pk0, pk1;
            pk0.u[0] = w0[0]; pk0.u[1] = w1[0]; pk0.u[2] = w0[1]; pk0.u[3] = w1[1];
            pk1.u[0] = w0[2]; pk1.u[1] = w1[2]; pk1.u[2] = w0[3]; pk1.u[3] = w1[3];
            __builtin_amdgcn_s_setprio(1);
#pragma unroll
            for (int df = 0; df < 4; df++) {
                oacc[df] = __builtin_amdgcn_mfma_f32_16x16x32_bf16(pk0.v8, vf[0][df], oacc[df], 0, 0, 0);
                oacc[df] = __builtin_amdgcn_mfma_f32_16x16x32_bf16(pk1.v8, vf[1][df], oacc[df], 0, 0, 0);
            }
            __builtin_amdgcn_s_setprio(0);
        }

        cur = (cur == 2) ? 0 : cur + 1;
    }
    lsum += __shfl_xor(lsum, 16);
    lsum += __shfl_xor(lsum, 32);
    if (lg == 0)
        atomicAdd(&Lacc[h * TFDIM + qbase + qh * 64 + wq * 16 + lr], lsum);
    if (PART) {
        unsigned short* PO = (c < 2) ? (PO01 + (size_t)c * SLOTSZ)
                                     : (PO23 + (size_t)(c - 2) * SLOTSZ);
#pragma unroll
        for (int df = 0; df < 4; df++)
#pragma unroll
            for (int r2 = 0; r2 < 4; r2++) {
                int row = qbase + qh * 64 + wq * 16 + lg * 4 + r2;
                PO[((size_t)h * TFDIM + row) * 64 + df * 16 + lr] = f2bf(oacc[df][r2]);
            }
    } else {
#pragma unroll
        for (int df = 0; df < 4; df++)
#pragma unroll
            for (int r2 = 0; r2 < 4; r2++) {
                int row = qbase + qh * 64 + wq * 16 + lg * 4 + r2;
                atomicAdd(&Oacc[(size_t)row * DMODEL + h * HDIM + df * 16 + lr], oacc[df][r2]);
            }
    }
}

// normalize (PART=0 path): ob = bf16(Oacc / Lacc)
__global__ void merge_kernel(const float* __restrict__ Oacc, const float* __restrict__ Lacc,
                             unsigned short* __restrict__ ob) {
    int i = blockIdx.x * 256 + threadIdx.x;
    if (i >= TFDIM * DMODEL / 4) return;
    int col4 = i % (DMODEL / 4), row = i / (DMODEL / 4);
    float4 v = ((const float4*)Oacc)[i];
    int h = col4 >> 4;
    float rl = 1.0f / Lacc[h * TFDIM + row];
    ushort4 u;
    u.x = f2bf(v.x * rl); u.y = f2bf(v.y * rl); u.z = f2bf(v.z * rl); u.w = f2bf(v.w * rl);
    ((ushort4*)ob)[i] = u;
}

// ---------------- launch ----------------

extern "C" void kernel_launch(void* const* d_in, const int* in_sizes, int n_in,
                              void* d_out, int out_size, void* d_ws, size_t ws_size,
                              hipStream_t stream) {
    const float* x  = (const float*)d_in[0];
    const float* Wq = (const float*)d_in[1];
    const float* bq = (const float*)d_in[2];
    const float* Wk = (const float*)d_in[3];
    const float* bk = (const float*)d_in[4];
    const float* Wv = (const float*)d_in[5];
    const float* bv = (const float*)d_in[6];
    const float* Wo = (const float*)d_in[7];
    const float* bo = (const float*)d_in[8];
    float* out = (float*)d_out;
    char* ws = (char*)d_ws;
    const unsigned short* dummyA = (const unsigned short*)d_ws;

    if (ws_size >= 45416448) {
        // branch 3 (r30 + fused merge): non-atomic bf16 partial slots, summed
        // directly inside GEMM3's A-staging (4 dispatches total).
        unsigned short* xb     = (unsigned short*)(ws + 0);
        unsigned short* PO01   = (unsigned short*)(ws + 0);
        unsigned short* WtQ    = (unsigned short*)(ws + 6291456);
        float*          bqkv   = (float*)(ws + 9830400);
        unsigned short* qkb    = (unsigned short*)(ws + 12582912);
        unsigned short* vtg    = (unsigned short*)(ws + 25165824);
        unsigned short* Wot    = (unsigned short*)(ws + 31457280);
        float*          Lacc   = (float*)(ws + 32636928);
        unsigned short* PO23   = (unsigned short*)(ws + 32833536);

        prep_kernel<<<3696, 256, 0, stream>>>(x, xb, Wq, Wk, Wv, bq, bk, bv, WtQ, bqkv, Wo, Wot, Lacc, nullptr);

        dim3 g1(2304 / 128, 4096 / 128);
        gemm_bt_kernel<1, 0><<<g1, 256, 0, stream>>>(xb, nullptr, nullptr, nullptr, WtQ, bqkv, nullptr, qkb, vtg, 4096, 2304, 768);

        attn_kernel<1><<<960, 512, 0, stream>>>(qkb, vtg, nullptr, Lacc, PO01, PO23);

        dim3 g3(768 / 128, 4096 / 128);
        gemm_bt_kernel<0, 2><<<g3, 256, 0, stream>>>(dummyA, PO01, PO23, Lacc, Wot, bo, out, nullptr, nullptr, 4096, 768, 768);
    } else if (ws_size >= 32833536) {
        // branch 2: atomic Oacc overlays xb; memset between GEMM1 and attn
        float*          Oacc = (float*)(ws + 0);
        unsigned short* xb   = (unsigned short*)(ws + 0);
        unsigned short* WtQ  = (unsigned short*)(ws + 6291456);
        float*          bqkv = (float*)(ws + 9830400);
        unsigned short* qkb  = (unsigned short*)(ws + 12582912);
        unsigned short* ob2  = (unsigned short*)(ws + 12582912);
        unsigned short* vtg  = (unsigned short*)(ws + 25165824);
        unsigned short* Wot  = (unsigned short*)(ws + 31457280);
        float*          Lacc = (float*)(ws + 32636928);

        prep_kernel<<<3696, 256, 0, stream>>>(x, xb, Wq, Wk, Wv, bq, bk, bv, WtQ, bqkv, Wo, Wot, Lacc, nullptr);

        dim3 g1(2304 / 128, 4096 / 128);
        gemm_bt_kernel<1, 0><<<g1, 256, 0, stream>>>(xb, nullptr, nullptr, nullptr, WtQ, bqkv, nullptr, qkb, vtg, 4096, 2304, 768);

        hipMemsetAsync(Oacc, 0, (size_t)TFDIM * DMODEL * 4, stream);

        attn_kernel<0><<<960, 512, 0, stream>>>(qkb, vtg, Oacc, Lacc, nullptr, nullptr);

        merge_kernel<<<(TFDIM * DMODEL / 4 + 255) / 256, 256, 0, stream>>>(Oacc, Lacc, ob2);

        dim3 g3(768 / 128, 4096 / 128);
        gemm_bt_kernel<0, 0><<<g3, 256, 0, stream>>>(ob2, nullptr, nullptr, nullptr, Wot, bo, out, nullptr, nullptr, 4096, 768, 768);
    } else {
        unsigned short* xb   = (unsigned short*)(ws + 0);
        unsigned short* ob   = (unsigned short*)(ws + 0);
        unsigned short* WtQ  = (unsigned short*)(ws + 6291456);
        unsigned short* Wot  = (unsigned short*)(ws + 9830400);
        float*          bqkv = (float*)(ws + 11010048);
        unsigned short* qkb  = (unsigned short*)(ws + 11019264);
        unsigned short* vtg  = (unsigned short*)(ws + 23602176);
        float*          Lacc = (float*)(ws + 29893632);
        float*          Oacc = out;

        hipMemsetAsync(Oacc, 0, (size_t)TFDIM * DMODEL * 4, stream);
        prep_kernel<<<3696, 256, 0, stream>>>(x, xb, Wq, Wk, Wv, bq, bk, bv, WtQ, bqkv, Wo, Wot, Lacc, nullptr);

        dim3 g1(2304 / 128, 4096 / 128);
        gemm_bt_kernel<1, 0><<<g1, 256, 0, stream>>>(xb, nullptr, nullptr, nullptr, WtQ, bqkv, nullptr, qkb, vtg, 4096, 2304, 768);

        attn_kernel<0><<<960, 512, 0, stream>>>(qkb, vtg, Oacc, Lacc, nullptr, nullptr);
        merge_kernel<<<(TFDIM * DMODEL / 4 + 255) / 256, 256, 0, stream>>>(Oacc, Lacc, ob);

        dim3 g3(768 / 128, 4096 / 128);
        gemm_bt_kernel<0, 0><<<g3, 256, 0, stream>>>(ob, nullptr, nullptr, nullptr, Wot, bo, out, nullptr, nullptr, 4096, 768, 768);
    }
}

// Round 32
// 107.557 us; speedup vs baseline: 1.3068x; 1.3068x over previous
//
#include <hip/hip_runtime.h>
#include <hip/hip_bf16.h>

typedef __attribute__((ext_vector_type(4))) float f32x4;
typedef __attribute__((ext_vector_type(8))) short s16x8;
typedef __attribute__((ext_vector_type(4))) int i32x4;
typedef __attribute__((address_space(3))) unsigned char lds_t;
typedef __attribute__((address_space(1))) const unsigned char glob_t;

#define TFDIM 4096
#define DMODEL 768
#define NHEAD 12
#define HDIM 64
#define NLB 6
#define SLOTSZ 3145728   // shorts per partial slot: 12*4096*64

static __device__ __forceinline__ unsigned short f2bf(float f) {
    union { float f; unsigned u; } x; x.f = f;
    unsigned r = x.u + 0x7fff + ((x.u >> 16) & 1);
    return (unsigned short)(r >> 16);
}

static __device__ __forceinline__ float bf2f(unsigned short u) {
    return __uint_as_float(((unsigned)u) << 16);
}

static __device__ __forceinline__ float exp2_hw(float x) {
    float r;
    asm("v_exp_f32 %0, %1\n\ts_nop 0" : "=v"(r) : "v"(x));
    return r;
}

static __device__ __forceinline__ unsigned cvtpk_bf16(float lo, float hi) {
    unsigned r;
    asm("v_cvt_pk_bf16_f32 %0, %1, %2" : "=v"(r) : "v"(lo), "v"(hi));
    return r;
}

// swap32 then swap16: from packed S-pairs (w_f, w_{f+1}) produce A0 (a) and A2 (b)
static __device__ __forceinline__ void xpose_pair(unsigned& a, unsigned& b) {
    asm volatile("v_permlane32_swap_b32 %0, %1" : "+v"(a), "+v"(b));
    asm volatile("v_permlane16_swap_b32 %0, %1" : "+v"(a), "+v"(b));
}

// ---------------- combined prep kernel ----------------
// blocks [0,432): wqkv transpose tiles; [432,576): wo transpose tiles;
// [576,624): Lacc zero; [624,3696): pack_x; [3696,6768): Oacc zero (branch-2 unused).
__global__ __launch_bounds__(256) void prep_kernel(
    const float* __restrict__ x, unsigned short* __restrict__ xb,
    const float* __restrict__ Wq, const float* __restrict__ Wk, const float* __restrict__ Wv,
    const float* __restrict__ bq, const float* __restrict__ bk, const float* __restrict__ bv,
    unsigned short* __restrict__ Wt, float* __restrict__ bias,
    const float* __restrict__ Wo, unsigned short* __restrict__ Wot,
    float* __restrict__ Lacc, float* __restrict__ Oacc) {
    __shared__ unsigned short tile[64][65];
    int b = blockIdx.x;
    int t = threadIdx.x;
    if (b < 432) {
        int qkv = b / 144, rem = b - qkv * 144, h = rem / 12, kt = rem - h * 12;
        const float* W = (qkv == 0) ? Wq : ((qkv == 1) ? Wk : Wv);
        int trow = t >> 2, tco = (t & 3) << 4;
        const float* src = &W[((size_t)h * 768 + kt * 64 + trow) * 64 + tco];
#pragma unroll
        for (int j = 0; j < 4; j++) {
            float4 v = *(const float4*)&src[j * 4];
            tile[trow][tco + j * 4 + 0] = f2bf(v.x);
            tile[trow][tco + j * 4 + 1] = f2bf(v.y);
            tile[trow][tco + j * 4 + 2] = f2bf(v.z);
            tile[trow][tco + j * 4 + 3] = f2bf(v.w);
        }
        if (kt == 0 && t < 64) {
            const float* bb = (qkv == 0) ? bq : ((qkv == 1) ? bk : bv);
            bias[qkv * 768 + h * 64 + t] = bb[h * 64 + t];
        }
        __syncthreads();
        unsigned short vals[16];
#pragma unroll
        for (int j = 0; j < 16; j++) vals[j] = tile[tco + j][trow];
        unsigned short* dst = &Wt[(size_t)(qkv * 768 + h * 64 + trow) * 768 + kt * 64 + tco];
        *(s16x8*)&dst[0] = *(const s16x8*)&vals[0];
        *(s16x8*)&dst[8] = *(const s16x8*)&vals[8];
    } else if (b < 576) {
        int bb = b - 432;
        int nt = bb / 12, kt = bb - nt * 12;
        int trow = t >> 2, tco = (t & 3) << 4;
        const float* src = &Wo[(size_t)(kt * 64 + trow) * 768 + nt * 64 + tco];
#pragma unroll
        for (int j = 0; j < 4; j++) {
            float4 v = *(const float4*)&src[j * 4];
            tile[trow][tco + j * 4 + 0] = f2bf(v.x);
            tile[trow][tco + j * 4 + 1] = f2bf(v.y);
            tile[trow][tco + j * 4 + 2] = f2bf(v.z);
            tile[trow][tco + j * 4 + 3] = f2bf(v.w);
        }
        __syncthreads();
        unsigned short vals[16];
#pragma unroll
        for (int j = 0; j < 16; j++) vals[j] = tile[tco + j][trow];
        unsigned short* dst = &Wot[(size_t)(nt * 64 + trow) * 768 + kt * 64 + tco];
        *(s16x8*)&dst[0] = *(const s16x8*)&vals[0];
        *(s16x8*)&dst[8] = *(const s16x8*)&vals[8];
    } else if (b < 624) {
        int i = (b - 576) * 256 + t;
        if (i < NHEAD * TFDIM / 4) {
            float4 z = {0.f, 0.f, 0.f, 0.f};
            ((float4*)Lacc)[i] = z;
        }
    } else if (b < 3696) {
        int i = (b - 624) * 256 + t;
        if (i < TFDIM * DMODEL / 4) {
            float4 v = ((const float4*)x)[i];
            ushort4 o;
            o.x = f2bf(v.x); o.y = f2bf(v.y); o.z = f2bf(v.z); o.w = f2bf(v.w);
            ((ushort4*)xb)[i] = o;
        }
    } else {
        int i = (b - 3696) * 256 + t;
        if (i < TFDIM * DMODEL / 4) {
            float4 z = {0.f, 0.f, 0.f, 0.f};
            ((float4*)Oacc)[i] = z;
        }
    }
}

// ---------------- GEMM: C = A[M,K] * Bt[N,K]^T + bias ----------------
// BK=64, [128][64]-short LDS tiles, full 8-granule XOR swizzle (slot ^ (row&7)),
// DMA staging with pre-swizzled global source. 2:1 MFMA:ds_read, 24 barriers.
// EPI 0: fp32 row-major C. EPI 1: Q (pre-scaled log2e/8), K blocked64 (nbase<1536);
//        V blocks (nbase>=1536): LDS-transpose epilogue -> coalesced Vtg writes.
// NOTE (r24/r31 measured twice): A must be DMA-staged; reg-staged A costs 15-50us.
template <int EPI, int ANORM>
__global__ __launch_bounds__(256) void gemm_bt_kernel(
    const unsigned short* __restrict__ A,
    const float* __restrict__ Af32, const float* __restrict__ Lacc,
    const unsigned short* __restrict__ Bt,
    const float* __restrict__ bias,
    float* __restrict__ Cf, unsigned short* __restrict__ Cb,
    unsigned short* __restrict__ Vtg,
    int M, int N, int K) {
    __shared__ __align__(16) unsigned short As[128 * 64];
    __shared__ __align__(16) unsigned short Bs[128 * 64];
    int tid = threadIdx.x;
    int w = tid >> 6, l = tid & 63, lr = l & 15, lg = l >> 4;
    int wm = w >> 1, wn = w & 1;

    int nwg = gridDim.x * gridDim.y;
    int flat = blockIdx.y * gridDim.x + blockIdx.x;
    int cpx = nwg >> 3;
    int swz = (flat & 7) * cpx + (flat >> 3);
    int bx = swz % gridDim.x, by = swz / gridDim.x;
    size_t mbase = (size_t)by * 128, nbase = (size_t)bx * 128;

    int drw = l >> 3, dslot = l & 7;
    int dg = (dslot ^ drw) << 3;
    f32x4 acc[4][4] = {};
    for (int k0 = 0; k0 < K; k0 += 64) {
        __syncthreads();
        if (ANORM) {
#pragma unroll
            for (int i = 0; i < 4; i++) {
                int idx = tid + i * 256;
                int row = idx >> 3, g = idx & 7;
                const float* src = &Af32[(mbase + row) * K + k0 + g * 8];
                float4 a0 = *(const float4*)&src[0];
                float4 a1 = *(const float4*)&src[4];
                float rl = __builtin_amdgcn_rcpf(Lacc[(size_t)(k0 >> 6) * TFDIM + mbase + row]);
                unsigned short us[8];
                us[0] = f2bf(a0.x * rl); us[1] = f2bf(a0.y * rl);
                us[2] = f2bf(a0.z * rl); us[3] = f2bf(a0.w * rl);
                us[4] = f2bf(a1.x * rl); us[5] = f2bf(a1.y * rl);
                us[6] = f2bf(a1.z * rl); us[7] = f2bf(a1.w * rl);
                *(s16x8*)&As[row * 64 + ((g ^ (row & 7)) << 3)] = *(const s16x8*)us;
            }
        } else {
#pragma unroll
            for (int j = 0; j < 4; j++) {
                int row = j * 32 + w * 8 + drw;
                __builtin_amdgcn_global_load_lds((glob_t*)&A[(mbase + row) * K + k0 + dg],
                                                 (lds_t*)&As[(j * 32 + w * 8) * 64], 16, 0, 0);
            }
        }
#pragma unroll
        for (int j = 0; j < 4; j++) {
            int row = j * 32 + w * 8 + drw;
            __builtin_amdgcn_global_load_lds((glob_t*)&Bt[(nbase + row) * K + k0 + dg],
                                             (lds_t*)&Bs[(j * 32 + w * 8) * 64], 16, 0, 0);
        }
        __syncthreads();
#pragma unroll
        for (int ks = 0; ks < 2; ks++) {
            s16x8 af[4], bfr[4];
#pragma unroll
            for (int m = 0; m < 4; m++) {
                int row = wm * 64 + m * 16 + lr;
                af[m] = *(const s16x8*)&As[row * 64 + (((ks * 4 + lg) ^ (row & 7)) << 3)];
            }
#pragma unroll
            for (int n = 0; n < 4; n++) {
                int row = wn * 64 + n * 16 + lr;
                bfr[n] = *(const s16x8*)&Bs[row * 64 + (((ks * 4 + lg) ^ (row & 7)) << 3)];
            }
#pragma unroll
            for (int m = 0; m < 4; m++)
#pragma unroll
                for (int n = 0; n < 4; n++)
                    acc[m][n] = __builtin_amdgcn_mfma_f32_16x16x32_bf16(af[m], bfr[n], acc[m][n], 0, 0, 0);
        }
    }
    if (EPI == 1 && nbase >= 1536) {
        // V-block: LDS-bounce transpose -> coalesced Vtg writes.
        __syncthreads();
        unsigned short* L = (w < 2) ? &As[w * 4096] : &Bs[(w - 2) * 4096];
#pragma unroll
        for (int n = 0; n < 4; n++) {
            int dloc = n * 16 + lr;
            float bv = bias[nbase + wn * 64 + dloc];
            int sw = (dloc & 7) << 3;
#pragma unroll
            for (int m = 0; m < 4; m++) {
                int tokloc = m * 16 + lg * 4;
                uint2 pw;
                pw.x = cvtpk_bf16(acc[m][n][0] + bv, acc[m][n][1] + bv);
                pw.y = cvtpk_bf16(acc[m][n][2] + bv, acc[m][n][3] + bv);
                *(uint2*)&L[dloc * 64 + (tokloc ^ sw)] = pw;
            }
        }
        __asm__ volatile("" ::: "memory");
        int hq = ((int)(nbase - 1536) >> 6) + wn;
        size_t vbase = (size_t)hq * 262144 + mbase + wm * 64;
#pragma unroll
        for (int it = 0; it < 8; it++) {
            int dl = it * 8 + (l >> 3);
            int t0 = (l & 7) * 8;
            s16x8 vv = *(const s16x8*)&L[dl * 64 + (t0 ^ ((dl & 7) << 3))];
            *(s16x8*)&Vtg[vbase + (size_t)dl * 4096 + t0] = vv;
        }
    } else {
#pragma unroll
        for (int m = 0; m < 4; m++) {
            size_t row0 = mbase + wm * 64 + m * 16 + lg * 4;
#pragma unroll
            for (int n = 0; n < 4; n++) {
                size_t col = nbase + wn * 64 + n * 16 + lr;
                float bv = bias[col];
#pragma unroll
                for (int r = 0; r < 4; r++) {
                    float v = acc[m][n][r] + bv;
                    if (EPI == 0) {
                        Cf[(row0 + r) * N + col] = v;
                    } else {
                        if (col < 768) v *= 0.18033688f;  // Q pre-scale: log2(e)/8
                        Cb[(((col >> 6) * 4096 + (row0 + r)) << 6) + (col & 63)] = f2bf(v);
                    }
                }
            }
        }
    }
}

// ---------------- flash attention, QBLK=128, 8 waves, kv-split chunks ----------------
// XCD head-clustering (r30 validated, FETCH -33%). PART=0: fp32 atomics.
// PART=1: non-atomic bf16 partial slots (r29, -11us).
template <int PART>
__global__ __launch_bounds__(512, 4) void attn_kernel(const unsigned short* __restrict__ qk,
                                                      const unsigned short* __restrict__ vtg,
                                                      float* __restrict__ Oacc,
                                                      float* __restrict__ Lacc,
                                                      unsigned short* __restrict__ PO01,
                                                      unsigned short* __restrict__ PO23) {
    __shared__ __align__(16) unsigned short Ks[3][64][64];
    __shared__ __align__(16) unsigned short Vs[3][64][64];

    int b = blockIdx.x;
    int xc = b & 7, j = b >> 3;
    int t3 = j / 3, rsel = j - t3 * 3;
    int h, r;
    if (xc & 1) {
        int ffull = (3 * xc + 1) >> 1;
        if (rsel == 0)      { h = ffull;     r = 2 * t3; }
        else if (rsel == 1) { h = ffull;     r = 2 * t3 + 1; }
        else                { h = ffull - 1; r = 2 * t3 + 1; }
    } else {
        int ffull = (3 * xc) >> 1;
        if (rsel == 0)      { h = ffull;     r = 2 * t3; }
        else if (rsel == 1) { h = ffull;     r = 2 * t3 + 1; }
        else                { h = ffull + 1; r = 2 * t3; }
    }
    int idx = 79 - r;
    int jqw, c, n;
    if (idx < 8)       { jqw = idx;               c = 0;              n = 1; }
    else if (idx < 24) { jqw = 8 + ((idx - 8) >> 1);  c = (idx - 8) & 1;  n = 2; }
    else if (idx < 48) { jqw = 16 + (idx - 24) / 3;   c = (idx - 24) % 3; n = 3; }
    else               { jqw = 24 + ((idx - 48) >> 2); c = (idx - 48) & 3; n = 4; }
    int W = 2 * jqw + 2;
    int base = W / n, rem = W % n;
    int len = base + (c < rem ? 1 : 0);
    int s0 = c * base + (c < rem ? c : rem);
    bool causal = (h < NLB);
    int jq = causal ? jqw : (31 - jqw);
    int qbase = jq * 128;
    int dkb = 2 * jq;
    int kb0 = (causal ? 0 : (62 - 2 * jqw)) + s0;
    int kb1 = kb0 + len - 1;

    const unsigned short* Q  = qk + (size_t)h * TFDIM * HDIM;
    const unsigned short* Kp = qk + (size_t)(NHEAD + h) * TFDIM * HDIM;
    const unsigned short* Vt = vtg + (size_t)h * HDIM * TFDIM;

    int tid = threadIdx.x, w = tid >> 6, l = tid & 63, lr = l & 15, lg = l >> 4;
    int qh = w >> 2, wq = w & 3;       // q-half, wave-within-half
    int dk = dkb + qh;                 // this wave's diagonal kv-block

    s16x8 qf[2];
    {
        size_t qrow = (size_t)(qbase + qh * 64 + wq * 16 + lr);
        qf[0] = *(const s16x8*)&Q[qrow * HDIM + lg * 8];
        qf[1] = *(const s16x8*)&Q[qrow * HDIM + 32 + lg * 8];
    }
    f32x4 oacc[4] = {};
    float lsum = 0.f;

    int drow = tid >> 3, dseg = tid & 7;
    int sg0 = (dseg ^ (drow & 7)) << 3;
    auto stage = [&](int buf, int kv) {
        __builtin_amdgcn_global_load_lds((glob_t*)(Kp + (size_t)(kv * 64 + drow) * HDIM + sg0),
                                         (lds_t*)&Ks[buf][w * 8][0], 16, 0, 0);
        __builtin_amdgcn_global_load_lds((glob_t*)(Vt + (size_t)drow * TFDIM + kv * 64 + sg0),
                                         (lds_t*)&Vs[buf][w * 8][0], 16, 0, 0);
    };

    stage(0, kb0);

    int cur = 0;
    int qcol = wq * 16 + lr;
    for (int kb = kb0; kb <= kb1; kb++) {
        bool more = (kb < kb1);
        if (more) {
            int nxt = (cur == 2) ? 0 : cur + 1;
            stage(nxt, kb + 1);
            asm volatile("s_waitcnt vmcnt(2)" ::: "memory");
        } else {
            asm volatile("s_waitcnt vmcnt(0)" ::: "memory");
        }
        __builtin_amdgcn_s_barrier();
        __builtin_amdgcn_sched_barrier(0);

        int kvbase = kb * 64;
        s16x8 vf[2][4];
#pragma unroll
        for (int ks = 0; ks < 2; ks++)
#pragma unroll
            for (int df = 0; df < 4; df++)
                vf[ks][df] = *(const s16x8*)&Vs[cur][df * 16 + lr][(ks * 32 + lg * 8) ^ ((lr & 7) << 3)];
        f32x4 s[4];
        __builtin_amdgcn_s_setprio(1);
#pragma unroll
        for (int f = 0; f < 4; f++) {
            s16x8 kf0 = *(const s16x8*)&Ks[cur][f * 16 + lr][(lg * 8) ^ ((lr & 7) << 3)];
            s16x8 kf1 = *(const s16x8*)&Ks[cur][f * 16 + lr][(32 + lg * 8) ^ ((lr & 7) << 3)];
            f32x4 z = {0.f, 0.f, 0.f, 0.f};
            z = __builtin_amdgcn_mfma_f32_16x16x32_bf16(kf0, qf[0], z, 0, 0, 0);
            z = __builtin_amdgcn_mfma_f32_16x16x32_bf16(kf1, qf[1], z, 0, 0, 0);
            s[f] = z;
        }
        __builtin_amdgcn_s_setprio(0);

        bool skip = causal ? (kb > dk) : (kb < dk);
        if (!skip) {
            if (kb == dk) {
                int qi = qbase + qh * 64 + qcol;
#pragma unroll
                for (int f = 0; f < 4; f++)
#pragma unroll
                    for (int r2 = 0; r2 < 4; r2++) {
                        int ki = kvbase + f * 16 + lg * 4 + r2;
                        bool keep = causal ? (qi >= ki) : (qi <= ki);
                        if (!keep) s[f][r2] = -1e30f;
                    }
            }
            float ls = 0.f;
            unsigned w0[4], w1[4];
#pragma unroll
            for (int f = 0; f < 4; f++) {
                float p0 = exp2_hw(s[f][0]);
                float p1 = exp2_hw(s[f][1]);
                float p2 = exp2_hw(s[f][2]);
                float p3 = exp2_hw(s[f][3]);
                ls += (p0 + p1) + (p2 + p3);
                w0[f] = cvtpk_bf16(p0, p1);
                w1[f] = cvtpk_bf16(p2, p3);
            }
            lsum += ls;
            xpose_pair(w0[0], w0[1]);
            xpose_pair(w1[0], w1[1]);
            xpose_pair(w0[2], w0[3]);
            xpose_pair(w1[2], w1[3]);
            union { unsigned u[4]; s16x8 v8; } pk0, pk1;
            pk0.u[0] = w0[0]; pk0.u[1] = w1[0]; pk0.u[2] = w0[1]; pk0.u[3] = w1[1];
            pk1.u[0] = w0[2]; pk1.u[1] = w1[2]; pk1.u[2] = w0[3]; pk1.u[3] = w1[3];
            __builtin_amdgcn_s_setprio(1);
#pragma unroll
            for (int df = 0; df < 4; df++) {
                oacc[df] = __builtin_amdgcn_mfma_f32_16x16x32_bf16(pk0.v8, vf[0][df], oacc[df], 0, 0, 0);
                oacc[df] = __builtin_amdgcn_mfma_f32_16x16x32_bf16(pk1.v8, vf[1][df], oacc[df], 0, 0, 0);
            }
            __builtin_amdgcn_s_setprio(0);
        }

        cur = (cur == 2) ? 0 : cur + 1;
    }
    lsum += __shfl_xor(lsum, 16);
    lsum += __shfl_xor(lsum, 32);
    if (lg == 0)
        atomicAdd(&Lacc[h * TFDIM + qbase + qh * 64 + wq * 16 + lr], lsum);
    if (PART) {
        unsigned short* PO = (c < 2) ? (PO01 + (size_t)c * SLOTSZ)
                                     : (PO23 + (size_t)(c - 2) * SLOTSZ);
#pragma unroll
        for (int df = 0; df < 4; df++)
#pragma unroll
            for (int r2 = 0; r2 < 4; r2++) {
                int row = qbase + qh * 64 + wq * 16 + lg * 4 + r2;
                PO[((size_t)h * TFDIM + row) * 64 + df * 16 + lr] = f2bf(oacc[df][r2]);
            }
    } else {
#pragma unroll
        for (int df = 0; df < 4; df++)
#pragma unroll
            for (int r2 = 0; r2 < 4; r2++) {
                int row = qbase + qh * 64 + wq * 16 + lg * 4 + r2;
                atomicAdd(&Oacc[(size_t)row * DMODEL + h * HDIM + df * 16 + lr], oacc[df][r2]);
            }
    }
}

// normalize (PART=0 path): ob = bf16(Oacc / Lacc)
__global__ void merge_kernel(const float* __restrict__ Oacc, const float* __restrict__ Lacc,
                             unsigned short* __restrict__ ob) {
    int i = blockIdx.x * 256 + threadIdx.x;
    if (i >= TFDIM * DMODEL / 4) return;
    int col4 = i % (DMODEL / 4), row = i / (DMODEL / 4);
    float4 v = ((const float4*)Oacc)[i];
    int h = col4 >> 4;
    float rl = 1.0f / Lacc[h * TFDIM + row];
    ushort4 u;
    u.x = f2bf(v.x * rl); u.y = f2bf(v.y * rl); u.z = f2bf(v.z * rl); u.w = f2bf(v.w * rl);
    ((ushort4*)ob)[i] = u;
}

// normalize (PART=1 path): sum n slots of bf16 partials, divide by Lacc, write ob.
__global__ void merge_part_kernel(const unsigned short* __restrict__ PO01,
                                  const unsigned short* __restrict__ PO23,
                                  const float* __restrict__ Lacc,
                                  unsigned short* __restrict__ ob) {
    int i = blockIdx.x * 256 + threadIdx.x;
    if (i >= TFDIM * 96) return;
    int row = i / 96, g = i - row * 96;
    int h = g >> 3, c0 = (g & 7) << 3;
    int jq = row >> 7;
    int jqw = (h < NLB) ? jq : (31 - jq);
    int n = 1 + (jqw >> 3);
    size_t off = ((size_t)h * TFDIM + row) * 64 + c0;
    float acc[8] = {};
    for (int s = 0; s < n; s++) {
        const unsigned short* PO = (s < 2) ? (PO01 + (size_t)s * SLOTSZ)
                                           : (PO23 + (size_t)(s - 2) * SLOTSZ);
        s16x8 v = *(const s16x8*)&PO[off];
#pragma unroll
        for (int j = 0; j < 8; j++) acc[j] += bf2f((unsigned short)v[j]);
    }
    float rl = 1.0f / Lacc[h * TFDIM + row];
    unsigned short o8[8];
#pragma unroll
    for (int j = 0; j < 8; j++) o8[j] = f2bf(acc[j] * rl);
    *(s16x8*)&ob[(size_t)row * DMODEL + h * HDIM + c0] = *(const s16x8*)o8;
}

// ---------------- launch ----------------

extern "C" void kernel_launch(void* const* d_in, const int* in_sizes, int n_in,
                              void* d_out, int out_size, void* d_ws, size_t ws_size,
                              hipStream_t stream) {
    const float* x  = (const float*)d_in[0];
    const float* Wq = (const float*)d_in[1];
    const float* bq = (const float*)d_in[2];
    const float* Wk = (const float*)d_in[3];
    const float* bk = (const float*)d_in[4];
    const float* Wv = (const float*)d_in[5];
    const float* bv = (const float*)d_in[6];
    const float* Wo = (const float*)d_in[7];
    const float* bo = (const float*)d_in[8];
    float* out = (float*)d_out;
    char* ws = (char*)d_ws;
    const unsigned short* dummyA = (const unsigned short*)d_ws;

    if (ws_size >= 45416448) {
        // branch 3 (r30 validated, 107.9us): non-atomic bf16 partial slots.
        unsigned short* xb     = (unsigned short*)(ws + 0);
        unsigned short* PO01   = (unsigned short*)(ws + 0);
        unsigned short* WtQ    = (unsigned short*)(ws + 6291456);
        float*          bqkv   = (float*)(ws + 9830400);
        unsigned short* qkb    = (unsigned short*)(ws + 12582912);
        unsigned short* ob2    = (unsigned short*)(ws + 12582912);  // alias: qkb dead after attn
        unsigned short* vtg    = (unsigned short*)(ws + 25165824);
        unsigned short* Wot    = (unsigned short*)(ws + 31457280);
        float*          Lacc   = (float*)(ws + 32636928);
        unsigned short* PO23   = (unsigned short*)(ws + 32833536);

        prep_kernel<<<3696, 256, 0, stream>>>(x, xb, Wq, Wk, Wv, bq, bk, bv, WtQ, bqkv, Wo, Wot, Lacc, nullptr);

        dim3 g1(2304 / 128, 4096 / 128);
        gemm_bt_kernel<1, 0><<<g1, 256, 0, stream>>>(xb, nullptr, nullptr, WtQ, bqkv, nullptr, qkb, vtg, 4096, 2304, 768);

        attn_kernel<1><<<960, 512, 0, stream>>>(qkb, vtg, nullptr, Lacc, PO01, PO23);

        merge_part_kernel<<<(TFDIM * 96 + 255) / 256, 256, 0, stream>>>(PO01, PO23, Lacc, ob2);

        dim3 g3(768 / 128, 4096 / 128);
        gemm_bt_kernel<0, 0><<<g3, 256, 0, stream>>>(ob2, nullptr, nullptr, Wot, bo, out, nullptr, nullptr, 4096, 768, 768);
    } else if (ws_size >= 32833536) {
        // branch 2: atomic Oacc overlays xb; memset between GEMM1 and attn
        float*          Oacc = (float*)(ws + 0);
        unsigned short* xb   = (unsigned short*)(ws + 0);
        unsigned short* WtQ  = (unsigned short*)(ws + 6291456);
        float*          bqkv = (float*)(ws + 9830400);
        unsigned short* qkb  = (unsigned short*)(ws + 12582912);
        unsigned short* ob2  = (unsigned short*)(ws + 12582912);
        unsigned short* vtg  = (unsigned short*)(ws + 25165824);
        unsigned short* Wot  = (unsigned short*)(ws + 31457280);
        float*          Lacc = (float*)(ws + 32636928);

        prep_kernel<<<3696, 256, 0, stream>>>(x, xb, Wq, Wk, Wv, bq, bk, bv, WtQ, bqkv, Wo, Wot, Lacc, nullptr);

        dim3 g1(2304 / 128, 4096 / 128);
        gemm_bt_kernel<1, 0><<<g1, 256, 0, stream>>>(xb, nullptr, nullptr, WtQ, bqkv, nullptr, qkb, vtg, 4096, 2304, 768);

        hipMemsetAsync(Oacc, 0, (size_t)TFDIM * DMODEL * 4, stream);

        attn_kernel<0><<<960, 512, 0, stream>>>(qkb, vtg, Oacc, Lacc, nullptr, nullptr);

        merge_kernel<<<(TFDIM * DMODEL / 4 + 255) / 256, 256, 0, stream>>>(Oacc, Lacc, ob2);

        dim3 g3(768 / 128, 4096 / 128);
        gemm_bt_kernel<0, 0><<<g3, 256, 0, stream>>>(ob2, nullptr, nullptr, Wot, bo, out, nullptr, nullptr, 4096, 768, 768);
    } else {
        unsigned short* xb   = (unsigned short*)(ws + 0);
        unsigned short* ob   = (unsigned short*)(ws + 0);
        unsigned short* WtQ  = (unsigned short*)(ws + 6291456);
        unsigned short* Wot  = (unsigned short*)(ws + 9830400);
        float*          bqkv = (float*)(ws + 11010048);
        unsigned short* qkb  = (unsigned short*)(ws + 11019264);
        unsigned short* vtg  = (unsigned short*)(ws + 23602176);
        float*          Lacc = (float*)(ws + 29893632);
        float*          Oacc = out;

        hipMemsetAsync(Oacc, 0, (size_t)TFDIM * DMODEL * 4, stream);
        prep_kernel<<<3696, 256, 0, stream>>>(x, xb, Wq, Wk, Wv, bq, bk, bv, WtQ, bqkv, Wo, Wot, Lacc, nullptr);

        dim3 g1(2304 / 128, 4096 / 128);
        gemm_bt_kernel<1, 0><<<g1, 256, 0, stream>>>(xb, nullptr, nullptr, WtQ, bqkv, nullptr, qkb, vtg, 4096, 2304, 768);

        attn_kernel<0><<<960, 512, 0, stream>>>(qkb, vtg, Oacc, Lacc, nullptr, nullptr);
        merge_kernel<<<(TFDIM * DMODEL / 4 + 255) / 256, 256, 0, stream>>>(Oacc, Lacc, ob);

        dim3 g3(768 / 128, 4096 / 128);
        gemm_bt_kernel<0, 0><<<g3, 256, 0, stream>>>(ob, nullptr, nullptr, Wot, bo, out, nullptr, nullptr, 4096, 768, 768);
    }
}